// Round 5
// baseline (396.286 us; speedup 1.0000x reference)
//
#include <hip/hip_runtime.h>
#include <hip/hip_bf16.h>
#include <hip/hip_cooperative_groups.h>

namespace cg = cooperative_groups;

// ---- problem constants: B=128, D=1024, ADA=1024, R=8, 4*D*R=32768 ----

typedef __attribute__((ext_vector_type(8))) __bf16 bf16x8;
typedef __attribute__((ext_vector_type(8))) short short8v;
typedef __attribute__((ext_vector_type(4))) float f32x4;

__device__ __forceinline__ float gelu_exact(float v) {
    return 0.5f * v * (1.0f + erff(v * 0.7071067811865476f));
}
__device__ __forceinline__ unsigned short f2bf(float f) {
    union { float f; unsigned u; } c; c.f = f;
    return (unsigned short)((c.u + 0x7FFFu + ((c.u >> 16) & 1u)) >> 16);
}

// ---------- MFMA GEMM core: acc += A[128 x K](bf16, row stride 1024) * B(f32->bf16) ----------
// BT=false: B[k][n] row-major (ld=ldb).  BT=true: B[k][n] = Bsrc[n][k]  (C = A * Bsrc^T)
// LDS double-buffered, 1 barrier per 64-wide k-step. SMEM = 27648 shorts (55296 B).
template <bool BT>
__device__ __forceinline__ void gemm_core(
    const unsigned short* __restrict__ A, const float* __restrict__ Bm,
    const int ldb, const int kchunk, const int k0base, const int n0,
    f32x4 (&acc)[4][2], unsigned short* __restrict__ SMEM)
{
    unsigned short* const AsB[2] = {SMEM, SMEM + 9216};
    unsigned short* const BsB[2] = {SMEM + 18432, SMEM + 23040};
    const int t = threadIdx.x;
    const int lane = t & 63, wid = t >> 6;
    const int wm = wid >> 1, wn = wid & 1;
    const int q = lane >> 4, c16 = lane & 15;

    // A staging map: 2 threads per row, 32 bf16 each
    const int arow = t >> 1, ahalf = t & 1;
    const unsigned short* aptr = A + arow * 1024 + k0base + ahalf * 32;
    const int adoff = arow * 72 + ahalf * 32;

    // B staging maps
    const int bnp = t & 31, bkc = t >> 5;   // !BT
    const int bnr = t >> 2, bpart = t & 3;  // BT
    const float* bptr = BT ? (Bm + (size_t)(n0 + bnr) * ldb + k0base + bpart * 16)
                           : (Bm + (size_t)(k0base + bkc * 8) * ldb + n0 + bnp * 2);

    short8v ra0, ra1, ra2, ra3;
    float2 rb0, rb1, rb2, rb3, rb4, rb5, rb6, rb7;  // !BT
    float4 rt0, rt1, rt2, rt3;                      // BT

    auto LOAD = [&](int kk) {
        const int koff = kk << 6;
        const unsigned short* ap = aptr + koff;
        ra0 = *(const short8v*)(ap);      ra1 = *(const short8v*)(ap + 8);
        ra2 = *(const short8v*)(ap + 16); ra3 = *(const short8v*)(ap + 24);
        if (!BT) {
            const float* bp = bptr + (size_t)koff * ldb;
            rb0 = *(const float2*)(bp);                    rb1 = *(const float2*)(bp + (size_t)ldb);
            rb2 = *(const float2*)(bp + (size_t)2 * ldb);  rb3 = *(const float2*)(bp + (size_t)3 * ldb);
            rb4 = *(const float2*)(bp + (size_t)4 * ldb);  rb5 = *(const float2*)(bp + (size_t)5 * ldb);
            rb6 = *(const float2*)(bp + (size_t)6 * ldb);  rb7 = *(const float2*)(bp + (size_t)7 * ldb);
        } else {
            const float* bp = bptr + koff;
            rt0 = *(const float4*)(bp);     rt1 = *(const float4*)(bp + 4);
            rt2 = *(const float4*)(bp + 8); rt3 = *(const float4*)(bp + 12);
        }
    };
    auto STORE_LDS = [&](int buf) {
        unsigned short* ad = AsB[buf] + adoff;
        *(short8v*)(ad)      = ra0; *(short8v*)(ad + 8)  = ra1;
        *(short8v*)(ad + 16) = ra2; *(short8v*)(ad + 24) = ra3;
        if (!BT) {
            short8v s0, s1;
            s0[0]=(short)f2bf(rb0.x); s1[0]=(short)f2bf(rb0.y);
            s0[1]=(short)f2bf(rb1.x); s1[1]=(short)f2bf(rb1.y);
            s0[2]=(short)f2bf(rb2.x); s1[2]=(short)f2bf(rb2.y);
            s0[3]=(short)f2bf(rb3.x); s1[3]=(short)f2bf(rb3.y);
            s0[4]=(short)f2bf(rb4.x); s1[4]=(short)f2bf(rb4.y);
            s0[5]=(short)f2bf(rb5.x); s1[5]=(short)f2bf(rb5.y);
            s0[6]=(short)f2bf(rb6.x); s1[6]=(short)f2bf(rb6.y);
            s0[7]=(short)f2bf(rb7.x); s1[7]=(short)f2bf(rb7.y);
            *(short8v*)(BsB[buf] + (bnp * 2 + 0) * 72 + bkc * 8) = s0;
            *(short8v*)(BsB[buf] + (bnp * 2 + 1) * 72 + bkc * 8) = s1;
        } else {
            short8v s0, s1;
            s0[0]=(short)f2bf(rt0.x); s0[1]=(short)f2bf(rt0.y); s0[2]=(short)f2bf(rt0.z); s0[3]=(short)f2bf(rt0.w);
            s0[4]=(short)f2bf(rt1.x); s0[5]=(short)f2bf(rt1.y); s0[6]=(short)f2bf(rt1.z); s0[7]=(short)f2bf(rt1.w);
            s1[0]=(short)f2bf(rt2.x); s1[1]=(short)f2bf(rt2.y); s1[2]=(short)f2bf(rt2.z); s1[3]=(short)f2bf(rt2.w);
            s1[4]=(short)f2bf(rt3.x); s1[5]=(short)f2bf(rt3.y); s1[6]=(short)f2bf(rt3.z); s1[7]=(short)f2bf(rt3.w);
            *(short8v*)(BsB[buf] + bnr * 72 + bpart * 16)     = s0;
            *(short8v*)(BsB[buf] + bnr * 72 + bpart * 16 + 8) = s1;
        }
    };

    const int nsteps = kchunk >> 6;
    LOAD(0);
    STORE_LDS(0);
    if (nsteps > 1) LOAD(1);
    __syncthreads();

    for (int kk = 0; kk < nsteps; ++kk) {
        if (kk + 1 < nsteps) STORE_LDS((kk + 1) & 1);
        if (kk + 2 < nsteps) LOAD(kk + 2);
        const unsigned short* Ab = AsB[kk & 1];
        const unsigned short* Bb = BsB[kk & 1];
        #pragma unroll
        for (int ks = 0; ks < 64; ks += 32) {
            bf16x8 af[4], bfv[2];
            #pragma unroll
            for (int mt = 0; mt < 4; ++mt)
                af[mt] = __builtin_bit_cast(bf16x8,
                    *(const short8v*)(Ab + (wm * 64 + mt * 16 + c16) * 72 + ks + q * 8));
            #pragma unroll
            for (int nt = 0; nt < 2; ++nt)
                bfv[nt] = __builtin_bit_cast(bf16x8,
                    *(const short8v*)(Bb + (wn * 32 + nt * 16 + c16) * 72 + ks + q * 8));
            #pragma unroll
            for (int mt = 0; mt < 4; ++mt)
                #pragma unroll
                for (int nt = 0; nt < 2; ++nt)
                    acc[mt][nt] = __builtin_amdgcn_mfma_f32_16x16x32_bf16(
                        af[mt], bfv[nt], acc[mt][nt], 0, 0, 0);
        }
        if (kk + 1 < nsteps) __syncthreads();
    }
    __syncthreads();  // protect SMEM reuse by next phase/user
}

// D-frag mapping: m = wm*64 + mt*16 + (lane>>4)*4 + j ; n = n0 + wn*32 + nt*16 + (lane&15)
__device__ __forceinline__ void store_tile(
    f32x4 (&acc)[4][2], float* __restrict__ C, const float* __restrict__ bias,
    const int ldc, const int n0)
{
    const int t = threadIdx.x, lane = t & 63, wid = t >> 6;
    const int wm = wid >> 1, wn = wid & 1, q = lane >> 4, c16 = lane & 15;
    #pragma unroll
    for (int mt = 0; mt < 4; ++mt) {
        const int m = wm * 64 + mt * 16 + q * 4;
        #pragma unroll
        for (int nt = 0; nt < 2; ++nt) {
            const int n = n0 + wn * 32 + nt * 16 + c16;
            const float bb = bias ? bias[n] : 0.0f;
            #pragma unroll
            for (int j = 0; j < 4; ++j)
                C[(size_t)(m + j) * ldc + n] = acc[mt][nt][j] + bb;
        }
    }
}

__device__ __forceinline__ void block_reduce8(float a[8], float* out8, float (*scr)[8], int t) {
    #pragma unroll
    for (int r = 0; r < 8; ++r)
        #pragma unroll
        for (int off = 32; off; off >>= 1)
            a[r] += __shfl_xor(a[r], off);
    if ((t & 63) == 0) {
        #pragma unroll
        for (int r = 0; r < 8; ++r) scr[t >> 6][r] = a[r];
    }
    __syncthreads();
    if (t < 8) out8[t] = scr[0][t] + scr[1][t] + scr[2][t] + scr[3][t];
    __syncthreads();
}

// =================== single cooperative mega-kernel, 512 blocks ===================
__global__ __launch_bounds__(256, 2) void mega_kernel(
    const float* __restrict__ x, const float* __restrict__ ada,
    const float* __restrict__ bup, const float* __restrict__ bdn,
    const float* __restrict__ ln_g, const float* __restrict__ ln_b,
    const float* __restrict__ W1, const float* __restrict__ b1,
    const float* __restrict__ W2, const float* __restrict__ b2,
    float* __restrict__ w, float* __restrict__ P1, float* __restrict__ P2s,
    unsigned short* __restrict__ cbf, unsigned short* __restrict__ xbf,
    unsigned short* __restrict__ hbf, unsigned short* __restrict__ ybf,
    float* __restrict__ out)
{
    cg::grid_group grid = cg::this_grid();
    __shared__ __align__(16) unsigned short SMEM[27648];   // 55296 B, shared by all phases
    const int bid = blockIdx.x, t = threadIdx.x;

    // ---------- P0: LayerNorm(ada)->cbf ; cast x->xbf  (blocks 0..127) ----------
    if (bid < 128) {
        const int b = bid;
        float* rs  = (float*)SMEM;       // [4]
        float* rss = (float*)SMEM + 4;   // [4]
        float4 v = ((const float4*)(ada + b * 1024))[t];
        float s  = v.x + v.y + v.z + v.w;
        float ss = v.x*v.x + v.y*v.y + v.z*v.z + v.w*v.w;
        #pragma unroll
        for (int off = 32; off; off >>= 1) { s += __shfl_xor(s, off); ss += __shfl_xor(ss, off); }
        if ((t & 63) == 0) { rs[t >> 6] = s; rss[t >> 6] = ss; }
        __syncthreads();
        float S  = rs[0] + rs[1] + rs[2] + rs[3];
        float SS = rss[0] + rss[1] + rss[2] + rss[3];
        float mu = S * (1.0f / 1024.0f);
        float rstd = rsqrtf(SS * (1.0f / 1024.0f) - mu * mu + 1e-5f);
        float4 gv = ((const float4*)ln_g)[t];
        float4 bv = ((const float4*)ln_b)[t];
        ushort4 o;
        o.x = f2bf((v.x - mu) * rstd * gv.x + bv.x);
        o.y = f2bf((v.y - mu) * rstd * gv.y + bv.y);
        o.z = f2bf((v.z - mu) * rstd * gv.z + bv.z);
        o.w = f2bf((v.w - mu) * rstd * gv.w + bv.w);
        ((ushort4*)(cbf + b * 1024))[t] = o;
        float4 xv = ((const float4*)(x + b * 1024))[t];
        ushort4 xo;
        xo.x = f2bf(xv.x); xo.y = f2bf(xv.y); xo.z = f2bf(xv.z); xo.w = f2bf(xv.w);
        ((ushort4*)(xbf + b * 1024))[t] = xo;
        __syncthreads();
    }
    grid.sync();

    // ---------- P1: GEMM1 split-K8 (blocks 0..127) + GEMM3 split-K8 (128..255) ----------
    if (bid < 256) {
        const bool g1 = bid < 128;
        const int lb = g1 ? bid : bid - 128;
        const int nt = lb >> 3, s = lb & 7;
        f32x4 acc[4][2] = {};
        gemm_core<false>(g1 ? cbf : xbf, g1 ? W1 : bdn, 1024, 128, s * 128, nt * 64, acc, SMEM);
        store_tile(acc, (g1 ? P1 : P2s) + s * 131072, nullptr, 1024, nt * 64);
    }
    grid.sync();

    // ---------- P2: hbf = bf16(gelu(sum P1 + b1))  (all 512 blocks) ----------
    {
        const int idx = bid * 256 + t;
        float s = b1[idx & 1023];
        #pragma unroll
        for (int p = 0; p < 8; ++p) s += P1[p * 131072 + idx];
        hbf[idx] = f2bf(gelu_exact(s));
    }
    grid.sync();

    // ---------- P3: GEMM2  w = hbf @ W2 + b2  (all 512 blocks, 64-col tiles) ----------
    {
        f32x4 acc[4][2] = {};
        gemm_core<false>(hbf, W2, 32768, 1024, 0, bid * 64, acc, SMEM);
        store_tile(acc, w, b2, 32768, bid * 64);
    }
    grid.sync();

    // ---------- P4: per-row epilogue (blocks 0..127): t2, y, ybf, t1, out-init ----------
    if (bid < 128) {
        const int b = bid;
        float (*scr)[8] = (float(*)[8])SMEM;          // 128 B
        float* t2s = (float*)SMEM + 32;               // 8
        float* t1s = (float*)SMEM + 40;               // 8
        const float* wrow = w + (size_t)b * 32768;
        const float* xrow = x + b * 1024;

        float a[8] = {0,0,0,0,0,0,0,0};
        #pragma unroll
        for (int i = 0; i < 4; ++i) {
            int d = t + i * 256;
            float xv = xrow[d];
            float4 w0 = *(const float4*)(wrow + 16384 + d * 8);
            float4 w1 = *(const float4*)(wrow + 16384 + d * 8 + 4);
            a[0] += xv * w0.x; a[1] += xv * w0.y; a[2] += xv * w0.z; a[3] += xv * w0.w;
            a[4] += xv * w1.x; a[5] += xv * w1.y; a[6] += xv * w1.z; a[7] += xv * w1.w;
        }
        block_reduce8(a, t2s, scr, t);
        float t2v[8];
        #pragma unroll
        for (int r = 0; r < 8; ++r) t2v[r] = t2s[r];

        float a1[8] = {0,0,0,0,0,0,0,0};
        #pragma unroll
        for (int i = 0; i < 4; ++i) {
            int l = t + i * 256;
            float s = 0.0f;
            #pragma unroll
            for (int p = 0; p < 8; ++p) s += P2s[p * 131072 + b * 1024 + l];
            float4 w0 = *(const float4*)(wrow + 24576 + l * 8);
            float4 w1 = *(const float4*)(wrow + 24576 + l * 8 + 4);
            s += w0.x*t2v[0] + w0.y*t2v[1] + w0.z*t2v[2] + w0.w*t2v[3]
               + w1.x*t2v[4] + w1.y*t2v[5] + w1.z*t2v[6] + w1.w*t2v[7];
            float y = gelu_exact(s);
            ybf[b * 1024 + l] = f2bf(y);
            float4 l0 = *(const float4*)(wrow + 8192 + l * 8);
            float4 l1 = *(const float4*)(wrow + 8192 + l * 8 + 4);
            a1[0] += y * l0.x; a1[1] += y * l0.y; a1[2] += y * l0.z; a1[3] += y * l0.w;
            a1[4] += y * l1.x; a1[5] += y * l1.y; a1[6] += y * l1.z; a1[7] += y * l1.w;
        }
        block_reduce8(a1, t1s, scr, t);
        float t1v[8];
        #pragma unroll
        for (int r = 0; r < 8; ++r) t1v[r] = t1s[r];

        #pragma unroll
        for (int i = 0; i < 4; ++i) {
            int k = t + i * 256;
            float4 w0 = *(const float4*)(wrow + k * 8);
            float4 w1 = *(const float4*)(wrow + k * 8 + 4);
            out[b * 1024 + k] = xrow[k]
               + w0.x*t1v[0] + w0.y*t1v[1] + w0.z*t1v[2] + w0.w*t1v[3]
               + w1.x*t1v[4] + w1.y*t1v[5] + w1.z*t1v[6] + w1.w*t1v[7];
        }
        __syncthreads();
    }
    grid.sync();

    // ---------- P5: GEMM4 split-K8 (blocks 0..127): partials of ybf @ bup^T -> P1 ----------
    if (bid < 128) {
        const int nt = bid >> 3, s = bid & 7;
        f32x4 acc[4][2] = {};
        gemm_core<true>(ybf, bup, 1024, 128, s * 128, nt * 64, acc, SMEM);
        store_tile(acc, P1 + s * 131072, nullptr, 1024, nt * 64);
    }
    grid.sync();

    // ---------- P6: out += sum GEMM4 partials (blocks 0..127, float4) ----------
    if (bid < 128) {
        const int idx4 = bid * 256 + t;   // float4 index, covers 131072 floats
        float4 o = ((float4*)out)[idx4];
        #pragma unroll
        for (int p = 0; p < 8; ++p) {
            float4 v = ((const float4*)(P1 + p * 131072))[idx4];
            o.x += v.x; o.y += v.y; o.z += v.z; o.w += v.w;
        }
        ((float4*)out)[idx4] = o;
    }
}

extern "C" void kernel_launch(void* const* d_in, const int* in_sizes, int n_in,
                              void* d_out, int out_size, void* d_ws, size_t ws_size,
                              hipStream_t stream) {
    (void)in_sizes; (void)n_in; (void)out_size; (void)ws_size;
    const float* x        = (const float*)d_in[0];
    const float* ada      = (const float*)d_in[1];
    const float* bup      = (const float*)d_in[2];
    const float* bdn      = (const float*)d_in[3];
    const float* ln_g     = (const float*)d_in[4];
    const float* ln_b     = (const float*)d_in[5];
    const float* W1       = (const float*)d_in[6];
    const float* b1       = (const float*)d_in[7];
    const float* W2       = (const float*)d_in[8];
    const float* b2       = (const float*)d_in[9];

    char* ws = (char*)d_ws;
    float* w            = (float*)(ws + 0);                  // 16 MiB
    float* P1           = (float*)(ws + 16777216);           // 4 MiB (8 slabs)
    float* P2s          = (float*)(ws + 20971520);           // 4 MiB (8 slabs)
    unsigned short* cbf = (unsigned short*)(ws + 25165824);  // 256 KiB each
    unsigned short* xbf = (unsigned short*)(ws + 25427968);
    unsigned short* hbf = (unsigned short*)(ws + 25690112);
    unsigned short* ybf = (unsigned short*)(ws + 25952256);
    float* outp         = (float*)d_out;

    void* args[] = {
        (void*)&x, (void*)&ada, (void*)&bup, (void*)&bdn,
        (void*)&ln_g, (void*)&ln_b, (void*)&W1, (void*)&b1,
        (void*)&W2, (void*)&b2,
        (void*)&w, (void*)&P1, (void*)&P2s,
        (void*)&cbf, (void*)&xbf, (void*)&hbf, (void*)&ybf,
        (void*)&outp
    };
    hipLaunchCooperativeKernel((const void*)mega_kernel, dim3(512), dim3(256),
                               args, 0, stream);
}

// Round 6
// 78.003 us; speedup vs baseline: 5.0804x; 5.0804x over previous
//
#include <hip/hip_runtime.h>
#include <hip/hip_bf16.h>

// ---- problem constants: B=128, D=1024, ADA=1024, R=8, 4*D*R=32768 ----

typedef __attribute__((ext_vector_type(8))) __bf16 bf16x8;
typedef __attribute__((ext_vector_type(8))) short short8v;
typedef __attribute__((ext_vector_type(4))) short short4v;
typedef __attribute__((ext_vector_type(4))) float f32x4;

__device__ __forceinline__ float gelu_exact(float v) {
    return 0.5f * v * (1.0f + erff(v * 0.7071067811865476f));
}
__device__ __forceinline__ unsigned short f2bf(float f) {
    union { float f; unsigned u; } c; c.f = f;
    return (unsigned short)((c.u + 0x7FFFu + ((c.u >> 16) & 1u)) >> 16);
}

// ---------- LayerNorm(ada_emb) -> c_bf16 ; cast x -> x_bf16 ----------
__global__ __launch_bounds__(256) void ln_cast_kernel(
    const float* __restrict__ ada, const float* __restrict__ g, const float* __restrict__ be,
    const float* __restrict__ x, unsigned short* __restrict__ cbf, unsigned short* __restrict__ xbf)
{
    int b = blockIdx.x, t = threadIdx.x;
    float4 v = ((const float4*)(ada + b * 1024))[t];
    float s  = v.x + v.y + v.z + v.w;
    float ss = v.x*v.x + v.y*v.y + v.z*v.z + v.w*v.w;
    #pragma unroll
    for (int off = 32; off; off >>= 1) { s += __shfl_xor(s, off); ss += __shfl_xor(ss, off); }
    __shared__ float rs[4], rss[4];
    int wid = t >> 6;
    if ((t & 63) == 0) { rs[wid] = s; rss[wid] = ss; }
    __syncthreads();
    float S  = rs[0] + rs[1] + rs[2] + rs[3];
    float SS = rss[0] + rss[1] + rss[2] + rss[3];
    float mu = S * (1.0f / 1024.0f);
    float rstd = rsqrtf(SS * (1.0f / 1024.0f) - mu * mu + 1e-5f);
    float4 gv = ((const float4*)g)[t];
    float4 bv = ((const float4*)be)[t];
    ushort4 o;
    o.x = f2bf((v.x - mu) * rstd * gv.x + bv.x);
    o.y = f2bf((v.y - mu) * rstd * gv.y + bv.y);
    o.z = f2bf((v.z - mu) * rstd * gv.z + bv.z);
    o.w = f2bf((v.w - mu) * rstd * gv.w + bv.w);
    ((ushort4*)(cbf + b * 1024))[t] = o;
    float4 xv = ((const float4*)(x + b * 1024))[t];
    ushort4 xo;
    xo.x = f2bf(xv.x); xo.y = f2bf(xv.y); xo.z = f2bf(xv.z); xo.w = f2bf(xv.w);
    ((ushort4*)(xbf + b * 1024))[t] = xo;
}

// ========== big-M GEMM core (M=128 x N=64 tile), used by GEMM2 ==========
// acc += A[128 x 1024](bf16) * B(f32->bf16); B[k][n] row-major (ld=ldb).
__device__ __forceinline__ void gemm_core(
    const unsigned short* __restrict__ A, const float* __restrict__ Bm,
    const int ldb, const int n0,
    f32x4 (&acc)[4][2], unsigned short* __restrict__ SMEM)
{
    unsigned short* const AsB[2] = {SMEM, SMEM + 9216};
    unsigned short* const BsB[2] = {SMEM + 18432, SMEM + 23040};
    const int t = threadIdx.x;
    const int lane = t & 63, wid = t >> 6;
    const int wm = wid >> 1, wn = wid & 1;
    const int q = lane >> 4, c16 = lane & 15;

    const int arow = t >> 1, ahalf = t & 1;
    const unsigned short* aptr = A + arow * 1024 + ahalf * 32;
    const int adoff = arow * 72 + ahalf * 32;

    const int bnp = t & 31, bkc = t >> 5;
    const float* bptr = Bm + (size_t)(bkc * 8) * ldb + n0 + bnp * 2;

    short8v ra0, ra1, ra2, ra3;
    float2 rb0, rb1, rb2, rb3, rb4, rb5, rb6, rb7;

    auto LOAD = [&](int kk) {
        const int koff = kk << 6;
        const unsigned short* ap = aptr + koff;
        ra0 = *(const short8v*)(ap);      ra1 = *(const short8v*)(ap + 8);
        ra2 = *(const short8v*)(ap + 16); ra3 = *(const short8v*)(ap + 24);
        const float* bp = bptr + (size_t)koff * ldb;
        rb0 = *(const float2*)(bp);                    rb1 = *(const float2*)(bp + (size_t)ldb);
        rb2 = *(const float2*)(bp + (size_t)2 * ldb);  rb3 = *(const float2*)(bp + (size_t)3 * ldb);
        rb4 = *(const float2*)(bp + (size_t)4 * ldb);  rb5 = *(const float2*)(bp + (size_t)5 * ldb);
        rb6 = *(const float2*)(bp + (size_t)6 * ldb);  rb7 = *(const float2*)(bp + (size_t)7 * ldb);
    };
    auto STORE_LDS = [&](int buf) {
        unsigned short* ad = AsB[buf] + adoff;
        *(short8v*)(ad)      = ra0; *(short8v*)(ad + 8)  = ra1;
        *(short8v*)(ad + 16) = ra2; *(short8v*)(ad + 24) = ra3;
        short8v s0, s1;
        s0[0]=(short)f2bf(rb0.x); s1[0]=(short)f2bf(rb0.y);
        s0[1]=(short)f2bf(rb1.x); s1[1]=(short)f2bf(rb1.y);
        s0[2]=(short)f2bf(rb2.x); s1[2]=(short)f2bf(rb2.y);
        s0[3]=(short)f2bf(rb3.x); s1[3]=(short)f2bf(rb3.y);
        s0[4]=(short)f2bf(rb4.x); s1[4]=(short)f2bf(rb4.y);
        s0[5]=(short)f2bf(rb5.x); s1[5]=(short)f2bf(rb5.y);
        s0[6]=(short)f2bf(rb6.x); s1[6]=(short)f2bf(rb6.y);
        s0[7]=(short)f2bf(rb7.x); s1[7]=(short)f2bf(rb7.y);
        *(short8v*)(BsB[buf] + (bnp * 2 + 0) * 72 + bkc * 8) = s0;
        *(short8v*)(BsB[buf] + (bnp * 2 + 1) * 72 + bkc * 8) = s1;
    };

    const int nsteps = 16;
    LOAD(0);
    STORE_LDS(0);
    LOAD(1);
    __syncthreads();

    for (int kk = 0; kk < nsteps; ++kk) {
        if (kk + 1 < nsteps) STORE_LDS((kk + 1) & 1);
        if (kk + 2 < nsteps) LOAD(kk + 2);
        const unsigned short* Ab = AsB[kk & 1];
        const unsigned short* Bb = BsB[kk & 1];
        #pragma unroll
        for (int ks = 0; ks < 64; ks += 32) {
            bf16x8 af[4], bfv[2];
            #pragma unroll
            for (int mt = 0; mt < 4; ++mt)
                af[mt] = __builtin_bit_cast(bf16x8,
                    *(const short8v*)(Ab + (wm * 64 + mt * 16 + c16) * 72 + ks + q * 8));
            #pragma unroll
            for (int nt = 0; nt < 2; ++nt)
                bfv[nt] = __builtin_bit_cast(bf16x8,
                    *(const short8v*)(Bb + (wn * 32 + nt * 16 + c16) * 72 + ks + q * 8));
            #pragma unroll
            for (int mt = 0; mt < 4; ++mt)
                #pragma unroll
                for (int nt = 0; nt < 2; ++nt)
                    acc[mt][nt] = __builtin_amdgcn_mfma_f32_16x16x32_bf16(
                        af[mt], bfv[nt], acc[mt][nt], 0, 0, 0);
        }
        if (kk + 1 < nsteps) __syncthreads();
    }
}

// ========== small-M GEMM core (M=16 x N=64 tile, full K=1024) ==========
// acc += A[m0:m0+16, :](bf16, ld 1024) * B(f32->bf16)
// BT=false: B[k][n] row-major (ld=ldb).  BT=true: B[k][n] = Bsrc[n][k].
// Wave wid computes C[0:16, wid*16 : wid*16+16]. LDS use: 11520 shorts.
template <bool BT>
__device__ __forceinline__ void gemm_mt_core(
    const unsigned short* __restrict__ A, const float* __restrict__ Bm,
    const int ldb, const int m0, const int n0,
    f32x4 &acc, unsigned short* __restrict__ SMEM)
{
    unsigned short* const AsB[2] = {SMEM, SMEM + 1152};
    unsigned short* const BsB[2] = {SMEM + 2304, SMEM + 6912};
    const int t = threadIdx.x;
    const int lane = t & 63, wid = t >> 6;
    const int q = lane >> 4, c16 = lane & 15;

    // A staging: 16 threads per row, 4 bf16 each
    const int arow = t >> 4, acol = (t & 15) * 4;
    const unsigned short* aptr = A + (m0 + arow) * 1024 + acol;
    const int adoff = arow * 72 + acol;

    // B staging maps (64 n x 64 k per step)
    const int bnp = t & 31, bkc = t >> 5;   // !BT
    const int bnr = t >> 2, bpart = t & 3;  // BT
    const float* bptr = BT ? (Bm + (size_t)(n0 + bnr) * ldb + bpart * 16)
                           : (Bm + (size_t)(bkc * 8) * ldb + n0 + bnp * 2);

    short4v ra;
    float2 rb0, rb1, rb2, rb3, rb4, rb5, rb6, rb7;  // !BT
    float4 rt0, rt1, rt2, rt3;                      // BT

    auto LOAD = [&](int kk) {
        const int koff = kk << 6;
        ra = *(const short4v*)(aptr + koff);
        if (!BT) {
            const float* bp = bptr + (size_t)koff * ldb;
            rb0 = *(const float2*)(bp);                    rb1 = *(const float2*)(bp + (size_t)ldb);
            rb2 = *(const float2*)(bp + (size_t)2 * ldb);  rb3 = *(const float2*)(bp + (size_t)3 * ldb);
            rb4 = *(const float2*)(bp + (size_t)4 * ldb);  rb5 = *(const float2*)(bp + (size_t)5 * ldb);
            rb6 = *(const float2*)(bp + (size_t)6 * ldb);  rb7 = *(const float2*)(bp + (size_t)7 * ldb);
        } else {
            const float* bp = bptr + koff;
            rt0 = *(const float4*)(bp);     rt1 = *(const float4*)(bp + 4);
            rt2 = *(const float4*)(bp + 8); rt3 = *(const float4*)(bp + 12);
        }
    };
    auto STORE_LDS = [&](int buf) {
        *(short4v*)(AsB[buf] + adoff) = ra;
        if (!BT) {
            short8v s0, s1;
            s0[0]=(short)f2bf(rb0.x); s1[0]=(short)f2bf(rb0.y);
            s0[1]=(short)f2bf(rb1.x); s1[1]=(short)f2bf(rb1.y);
            s0[2]=(short)f2bf(rb2.x); s1[2]=(short)f2bf(rb2.y);
            s0[3]=(short)f2bf(rb3.x); s1[3]=(short)f2bf(rb3.y);
            s0[4]=(short)f2bf(rb4.x); s1[4]=(short)f2bf(rb4.y);
            s0[5]=(short)f2bf(rb5.x); s1[5]=(short)f2bf(rb5.y);
            s0[6]=(short)f2bf(rb6.x); s1[6]=(short)f2bf(rb6.y);
            s0[7]=(short)f2bf(rb7.x); s1[7]=(short)f2bf(rb7.y);
            *(short8v*)(BsB[buf] + (bnp * 2 + 0) * 72 + bkc * 8) = s0;
            *(short8v*)(BsB[buf] + (bnp * 2 + 1) * 72 + bkc * 8) = s1;
        } else {
            short8v s0, s1;
            s0[0]=(short)f2bf(rt0.x); s0[1]=(short)f2bf(rt0.y); s0[2]=(short)f2bf(rt0.z); s0[3]=(short)f2bf(rt0.w);
            s0[4]=(short)f2bf(rt1.x); s0[5]=(short)f2bf(rt1.y); s0[6]=(short)f2bf(rt1.z); s0[7]=(short)f2bf(rt1.w);
            s1[0]=(short)f2bf(rt2.x); s1[1]=(short)f2bf(rt2.y); s1[2]=(short)f2bf(rt2.z); s1[3]=(short)f2bf(rt2.w);
            s1[4]=(short)f2bf(rt3.x); s1[5]=(short)f2bf(rt3.y); s1[6]=(short)f2bf(rt3.z); s1[7]=(short)f2bf(rt3.w);
            *(short8v*)(BsB[buf] + bnr * 72 + bpart * 16)     = s0;
            *(short8v*)(BsB[buf] + bnr * 72 + bpart * 16 + 8) = s1;
        }
    };

    const int nsteps = 16;
    LOAD(0);
    STORE_LDS(0);
    LOAD(1);
    __syncthreads();

    for (int kk = 0; kk < nsteps; ++kk) {
        if (kk + 1 < nsteps) STORE_LDS((kk + 1) & 1);
        if (kk + 2 < nsteps) LOAD(kk + 2);
        const unsigned short* Ab = AsB[kk & 1];
        const unsigned short* Bb = BsB[kk & 1];
        #pragma unroll
        for (int ks = 0; ks < 64; ks += 32) {
            bf16x8 af = __builtin_bit_cast(bf16x8,
                *(const short8v*)(Ab + c16 * 72 + ks + q * 8));
            bf16x8 bf = __builtin_bit_cast(bf16x8,
                *(const short8v*)(Bb + (wid * 16 + c16) * 72 + ks + q * 8));
            acc = __builtin_amdgcn_mfma_f32_16x16x32_bf16(af, bf, acc, 0, 0, 0);
        }
        if (kk + 1 < nsteps) __syncthreads();
    }
}

// ---- GEMM1 full-K M-split (128 blocks): hbf = bf16(gelu(cbf @ W1 + b1)) ----
__global__ __launch_bounds__(256, 2) void gemm1h_kernel(
    const unsigned short* __restrict__ cbf, const float* __restrict__ W1,
    const float* __restrict__ b1, unsigned short* __restrict__ hbf)
{
    __shared__ __align__(16) unsigned short SMEM[11520];
    const int m0 = (blockIdx.x & 7) * 16, n0 = (blockIdx.x >> 3) * 64;
    f32x4 acc = {};
    gemm_mt_core<false>(cbf, W1, 1024, m0, n0, acc, SMEM);
    const int t = threadIdx.x, lane = t & 63, wid = t >> 6;
    const int q = lane >> 4, c16 = lane & 15;
    const int n = n0 + wid * 16 + c16;
    const float bb = b1[n];
    #pragma unroll
    for (int j = 0; j < 4; ++j)
        hbf[(m0 + q * 4 + j) * 1024 + n] = f2bf(gelu_exact(acc[j] + bb));
}

// ---- mega launch: blocks 0..127 = GEMM3 full-K M-split (P2 = xbf @ bdn),
//                   blocks 128..639 = GEMM2 (w = hbf @ W2 + b2) ----
__global__ __launch_bounds__(256, 2) void gemm23_kernel(
    const unsigned short* __restrict__ hbf, const float* __restrict__ W2,
    const float* __restrict__ b2, float* __restrict__ w,
    const unsigned short* __restrict__ xbf, const float* __restrict__ bdn,
    float* __restrict__ P2)
{
    __shared__ __align__(16) unsigned short SMEM[27648];
    const int bid = blockIdx.x, t = threadIdx.x;
    if (bid < 128) {
        const int m0 = (bid & 7) * 16, n0 = (bid >> 3) * 64;
        f32x4 acc = {};
        gemm_mt_core<false>(xbf, bdn, 1024, m0, n0, acc, SMEM);
        const int lane = t & 63, wid = t >> 6;
        const int q = lane >> 4, c16 = lane & 15;
        const int n = n0 + wid * 16 + c16;
        #pragma unroll
        for (int j = 0; j < 4; ++j)
            P2[(m0 + q * 4 + j) * 1024 + n] = acc[j];
    } else {
        const int n0 = (bid - 128) * 64;
        f32x4 acc[4][2] = {};
        gemm_core(hbf, W2, 32768, n0, acc, SMEM);
        const int lane = t & 63, wid = t >> 6;
        const int wm = wid >> 1, wn = wid & 1, q = lane >> 4, c16 = lane & 15;
        #pragma unroll
        for (int mt = 0; mt < 4; ++mt) {
            const int m = wm * 64 + mt * 16 + q * 4;
            #pragma unroll
            for (int nt = 0; nt < 2; ++nt) {
                const int n = n0 + wn * 32 + nt * 16 + c16;
                const float bb = b2[n];
                #pragma unroll
                for (int j = 0; j < 4; ++j)
                    w[(size_t)(m + j) * 32768 + n] = acc[mt][nt][j] + bb;
            }
        }
    }
}

// ---- GEMM4 full-K M-split (128 blocks): out += ybf @ bup^T ----
__global__ __launch_bounds__(256, 2) void gemm4_kernel(
    const unsigned short* __restrict__ ybf, const float* __restrict__ bup,
    float* __restrict__ out)
{
    __shared__ __align__(16) unsigned short SMEM[11520];
    const int m0 = (blockIdx.x & 7) * 16, n0 = (blockIdx.x >> 3) * 64;
    f32x4 acc = {};
    gemm_mt_core<true>(ybf, bup, 1024, m0, n0, acc, SMEM);
    const int t = threadIdx.x, lane = t & 63, wid = t >> 6;
    const int q = lane >> 4, c16 = lane & 15;
    const int n = n0 + wid * 16 + c16;
    #pragma unroll
    for (int j = 0; j < 4; ++j)
        out[(m0 + q * 4 + j) * 1024 + n] += acc[j];
}

// ---------- per-row fused epilogue: t2, y=gelu(.), ybf, t1, out_init ----------
__device__ __forceinline__ void block_reduce8(float a[8], float* out8, float (*scr)[8], int t) {
    #pragma unroll
    for (int r = 0; r < 8; ++r)
        #pragma unroll
        for (int off = 32; off; off >>= 1)
            a[r] += __shfl_xor(a[r], off);
    if ((t & 63) == 0) {
        #pragma unroll
        for (int r = 0; r < 8; ++r) scr[t >> 6][r] = a[r];
    }
    __syncthreads();
    if (t < 8) out8[t] = scr[0][t] + scr[1][t] + scr[2][t] + scr[3][t];
    __syncthreads();
}

__global__ __launch_bounds__(256) void e1big_kernel(
    const float* __restrict__ P2, const float* __restrict__ w,
    const float* __restrict__ x, unsigned short* __restrict__ ybf,
    float* __restrict__ out)
{
    __shared__ float scr[4][8];
    __shared__ float t2s[8], t1s[8];
    const int b = blockIdx.x, t = threadIdx.x;
    const float* wrow = w + (size_t)b * 32768;
    const float* xrow = x + b * 1024;

    // stage 1: t2[r] = sum_d la2[b,d,r] * x[b,d]   (la2 = chunk 2 @ +16384)
    float a[8] = {0,0,0,0,0,0,0,0};
    #pragma unroll
    for (int i = 0; i < 4; ++i) {
        int d = t + i * 256;
        float xv = xrow[d];
        float4 w0 = *(const float4*)(wrow + 16384 + d * 8);
        float4 w1 = *(const float4*)(wrow + 16384 + d * 8 + 4);
        a[0] += xv * w0.x; a[1] += xv * w0.y; a[2] += xv * w0.z; a[3] += xv * w0.w;
        a[4] += xv * w1.x; a[5] += xv * w1.y; a[6] += xv * w1.z; a[7] += xv * w1.w;
    }
    block_reduce8(a, t2s, scr, t);
    float t2v[8];
    #pragma unroll
    for (int r = 0; r < 8; ++r) t2v[r] = t2s[r];

    // stage 2: y = gelu(P2 + lb2 @ t2); accumulate t1 = sum_l lb1[l,:]*y[l]
    float a1[8] = {0,0,0,0,0,0,0,0};
    #pragma unroll
    for (int i = 0; i < 4; ++i) {
        int l = t + i * 256;
        float s = P2[b * 1024 + l];
        float4 w0 = *(const float4*)(wrow + 24576 + l * 8);
        float4 w1 = *(const float4*)(wrow + 24576 + l * 8 + 4);
        s += w0.x*t2v[0] + w0.y*t2v[1] + w0.z*t2v[2] + w0.w*t2v[3]
           + w1.x*t2v[4] + w1.y*t2v[5] + w1.z*t2v[6] + w1.w*t2v[7];
        float y = gelu_exact(s);
        ybf[b * 1024 + l] = f2bf(y);
        float4 l0 = *(const float4*)(wrow + 8192 + l * 8);
        float4 l1 = *(const float4*)(wrow + 8192 + l * 8 + 4);
        a1[0] += y * l0.x; a1[1] += y * l0.y; a1[2] += y * l0.z; a1[3] += y * l0.w;
        a1[4] += y * l1.x; a1[5] += y * l1.y; a1[6] += y * l1.z; a1[7] += y * l1.w;
    }
    block_reduce8(a1, t1s, scr, t);
    float t1v[8];
    #pragma unroll
    for (int r = 0; r < 8; ++r) t1v[r] = t1s[r];

    // stage 3: out_init = x + la1 @ t1   (la1 = chunk 0)
    #pragma unroll
    for (int i = 0; i < 4; ++i) {
        int k = t + i * 256;
        float4 w0 = *(const float4*)(wrow + k * 8);
        float4 w1 = *(const float4*)(wrow + k * 8 + 4);
        out[b * 1024 + k] = xrow[k]
           + w0.x*t1v[0] + w0.y*t1v[1] + w0.z*t1v[2] + w0.w*t1v[3]
           + w1.x*t1v[4] + w1.y*t1v[5] + w1.z*t1v[6] + w1.w*t1v[7];
    }
}

extern "C" void kernel_launch(void* const* d_in, const int* in_sizes, int n_in,
                              void* d_out, int out_size, void* d_ws, size_t ws_size,
                              hipStream_t stream) {
    (void)in_sizes; (void)n_in; (void)out_size; (void)ws_size;
    const float* x        = (const float*)d_in[0];
    const float* ada      = (const float*)d_in[1];
    const float* bup      = (const float*)d_in[2];
    const float* bdn      = (const float*)d_in[3];
    const float* ln_g     = (const float*)d_in[4];
    const float* ln_b     = (const float*)d_in[5];
    const float* W1       = (const float*)d_in[6];
    const float* b1       = (const float*)d_in[7];
    const float* W2       = (const float*)d_in[8];
    const float* b2       = (const float*)d_in[9];

    char* ws = (char*)d_ws;
    float* w            = (float*)(ws + 0);                  // 16 MiB
    float* P2           = (float*)(ws + 16777216);           // 512 KiB
    unsigned short* cbf = (unsigned short*)(ws + 17301504);  // 256 KiB each
    unsigned short* xbf = (unsigned short*)(ws + 17563648);
    unsigned short* hbf = (unsigned short*)(ws + 17825792);
    unsigned short* ybf = (unsigned short*)(ws + 18087936);

    // 1. LN + bf16 casts
    ln_cast_kernel<<<128, 256, 0, stream>>>(ada, ln_g, ln_b, x, cbf, xbf);
    // 2. GEMM1 full-K M-split + gelu -> hbf
    gemm1h_kernel<<<128, 256, 0, stream>>>(cbf, W1, b1, hbf);
    // 3. GEMM3 (128 blocks, dispatched first) + GEMM2 (512 blocks)
    gemm23_kernel<<<640, 256, 0, stream>>>(hbf, W2, b2, w, xbf, bdn, P2);
    // 4. fused row epilogue: t2, y, ybf, t1, out = x + la1@t1
    e1big_kernel<<<128, 256, 0, stream>>>(P2, w, x, ybf, (float*)d_out);
    // 5. GEMM4 full-K M-split: out += y @ bup^T
    gemm4_kernel<<<128, 256, 0, stream>>>(ybf, bup, (float*)d_out);
}

// Round 7
// 74.344 us; speedup vs baseline: 5.3304x; 1.0492x over previous
//
#include <hip/hip_runtime.h>
#include <hip/hip_bf16.h>

// ---- problem constants: B=128, D=1024, ADA=1024, R=8, 4*D*R=32768 ----

typedef __attribute__((ext_vector_type(8))) __bf16 bf16x8;
typedef __attribute__((ext_vector_type(8))) short short8v;
typedef __attribute__((ext_vector_type(4))) float f32x4;

__device__ __forceinline__ float gelu_exact(float v) {
    return 0.5f * v * (1.0f + erff(v * 0.7071067811865476f));
}
__device__ __forceinline__ unsigned short f2bf(float f) {
    union { float f; unsigned u; } c; c.f = f;
    return (unsigned short)((c.u + 0x7FFFu + ((c.u >> 16) & 1u)) >> 16);
}
__device__ __forceinline__ float bf2f(unsigned short u) {
    union { float f; unsigned u32; } c; c.u32 = ((unsigned)u) << 16; return c.f;
}

// ---------- LayerNorm(ada_emb) -> c_bf16 ; cast x -> x_bf16 ----------
__global__ __launch_bounds__(256) void ln_cast_kernel(
    const float* __restrict__ ada, const float* __restrict__ g, const float* __restrict__ be,
    const float* __restrict__ x, unsigned short* __restrict__ cbf, unsigned short* __restrict__ xbf)
{
    int b = blockIdx.x, t = threadIdx.x;
    float4 v = ((const float4*)(ada + b * 1024))[t];
    float s  = v.x + v.y + v.z + v.w;
    float ss = v.x*v.x + v.y*v.y + v.z*v.z + v.w*v.w;
    #pragma unroll
    for (int off = 32; off; off >>= 1) { s += __shfl_xor(s, off); ss += __shfl_xor(ss, off); }
    __shared__ float rs[4], rss[4];
    int wid = t >> 6;
    if ((t & 63) == 0) { rs[wid] = s; rss[wid] = ss; }
    __syncthreads();
    float S  = rs[0] + rs[1] + rs[2] + rs[3];
    float SS = rss[0] + rss[1] + rss[2] + rss[3];
    float mu = S * (1.0f / 1024.0f);
    float rstd = rsqrtf(SS * (1.0f / 1024.0f) - mu * mu + 1e-5f);
    float4 gv = ((const float4*)g)[t];
    float4 bv = ((const float4*)be)[t];
    ushort4 o;
    o.x = f2bf((v.x - mu) * rstd * gv.x + bv.x);
    o.y = f2bf((v.y - mu) * rstd * gv.y + bv.y);
    o.z = f2bf((v.z - mu) * rstd * gv.z + bv.z);
    o.w = f2bf((v.w - mu) * rstd * gv.w + bv.w);
    ((ushort4*)(cbf + b * 1024))[t] = o;
    float4 xv = ((const float4*)(x + b * 1024))[t];
    ushort4 xo;
    xo.x = f2bf(xv.x); xo.y = f2bf(xv.y); xo.z = f2bf(xv.z); xo.w = f2bf(xv.w);
    ((ushort4*)(xbf + b * 1024))[t] = xo;
}

// ---------- MFMA GEMM body (round-3 proven): C = A[128xK](bf16) * B(f32->bf16) ----------
// BT=false: B[k][n] row-major (ld=ldb).  BT=true: B[k][n] = Bsrc[n][k]
template <bool BT>
__device__ __forceinline__ void gemm_body(
    const unsigned short* __restrict__ A, const float* __restrict__ Bm,
    float* __restrict__ C, const int ldb, const int ldc,
    const int kchunk, const int k0base, const int n0)
{
    __shared__ __align__(16) unsigned short As[2][128 * 72];
    __shared__ __align__(16) unsigned short Bs[2][64 * 72];
    const int t = threadIdx.x;
    const int lane = t & 63, wid = t >> 6;
    const int wm = wid >> 1, wn = wid & 1;
    const int q = lane >> 4, c16 = lane & 15;

    const int arow = t >> 1, ahalf = t & 1;
    const unsigned short* aptr = A + arow * 1024 + k0base + ahalf * 32;
    const int adoff = arow * 72 + ahalf * 32;

    const int bnp = t & 31, bkc = t >> 5;   // !BT
    const int bnr = t >> 2, bpart = t & 3;  // BT
    const float* bptr = BT ? (Bm + (size_t)(n0 + bnr) * ldb + k0base + bpart * 16)
                           : (Bm + (size_t)(k0base + bkc * 8) * ldb + n0 + bnp * 2);

    f32x4 acc[4][2] = {};
    short8v ra0, ra1, ra2, ra3;
    float2 rb0, rb1, rb2, rb3, rb4, rb5, rb6, rb7;
    float4 rt0, rt1, rt2, rt3;

    auto LOAD = [&](int kk) {
        const int koff = kk << 6;
        const unsigned short* ap = aptr + koff;
        ra0 = *(const short8v*)(ap);      ra1 = *(const short8v*)(ap + 8);
        ra2 = *(const short8v*)(ap + 16); ra3 = *(const short8v*)(ap + 24);
        if (!BT) {
            const float* bp = bptr + (size_t)koff * ldb;
            rb0 = *(const float2*)(bp);                    rb1 = *(const float2*)(bp + (size_t)ldb);
            rb2 = *(const float2*)(bp + (size_t)2 * ldb);  rb3 = *(const float2*)(bp + (size_t)3 * ldb);
            rb4 = *(const float2*)(bp + (size_t)4 * ldb);  rb5 = *(const float2*)(bp + (size_t)5 * ldb);
            rb6 = *(const float2*)(bp + (size_t)6 * ldb);  rb7 = *(const float2*)(bp + (size_t)7 * ldb);
        } else {
            const float* bp = bptr + koff;
            rt0 = *(const float4*)(bp);     rt1 = *(const float4*)(bp + 4);
            rt2 = *(const float4*)(bp + 8); rt3 = *(const float4*)(bp + 12);
        }
    };
    auto STORE_LDS = [&](int buf) {
        unsigned short* ad = &As[buf][adoff];
        *(short8v*)(ad)      = ra0; *(short8v*)(ad + 8)  = ra1;
        *(short8v*)(ad + 16) = ra2; *(short8v*)(ad + 24) = ra3;
        if (!BT) {
            short8v s0, s1;
            s0[0]=(short)f2bf(rb0.x); s1[0]=(short)f2bf(rb0.y);
            s0[1]=(short)f2bf(rb1.x); s1[1]=(short)f2bf(rb1.y);
            s0[2]=(short)f2bf(rb2.x); s1[2]=(short)f2bf(rb2.y);
            s0[3]=(short)f2bf(rb3.x); s1[3]=(short)f2bf(rb3.y);
            s0[4]=(short)f2bf(rb4.x); s1[4]=(short)f2bf(rb4.y);
            s0[5]=(short)f2bf(rb5.x); s1[5]=(short)f2bf(rb5.y);
            s0[6]=(short)f2bf(rb6.x); s1[6]=(short)f2bf(rb6.y);
            s0[7]=(short)f2bf(rb7.x); s1[7]=(short)f2bf(rb7.y);
            *(short8v*)(&Bs[buf][(bnp * 2 + 0) * 72 + bkc * 8]) = s0;
            *(short8v*)(&Bs[buf][(bnp * 2 + 1) * 72 + bkc * 8]) = s1;
        } else {
            short8v s0, s1;
            s0[0]=(short)f2bf(rt0.x); s0[1]=(short)f2bf(rt0.y); s0[2]=(short)f2bf(rt0.z); s0[3]=(short)f2bf(rt0.w);
            s0[4]=(short)f2bf(rt1.x); s0[5]=(short)f2bf(rt1.y); s0[6]=(short)f2bf(rt1.z); s0[7]=(short)f2bf(rt1.w);
            s1[0]=(short)f2bf(rt2.x); s1[1]=(short)f2bf(rt2.y); s1[2]=(short)f2bf(rt2.z); s1[3]=(short)f2bf(rt2.w);
            s1[4]=(short)f2bf(rt3.x); s1[5]=(short)f2bf(rt3.y); s1[6]=(short)f2bf(rt3.z); s1[7]=(short)f2bf(rt3.w);
            *(short8v*)(&Bs[buf][bnr * 72 + bpart * 16])     = s0;
            *(short8v*)(&Bs[buf][bnr * 72 + bpart * 16 + 8]) = s1;
        }
    };

    const int nsteps = kchunk >> 6;
    LOAD(0);
    STORE_LDS(0);
    if (nsteps > 1) LOAD(1);
    __syncthreads();

    for (int kk = 0; kk < nsteps; ++kk) {
        if (kk + 1 < nsteps) STORE_LDS((kk + 1) & 1);
        if (kk + 2 < nsteps) LOAD(kk + 2);
        const unsigned short* Ab = &As[kk & 1][0];
        const unsigned short* Bb = &Bs[kk & 1][0];
        #pragma unroll
        for (int ks = 0; ks < 64; ks += 32) {
            bf16x8 af[4], bfv[2];
            #pragma unroll
            for (int mt = 0; mt < 4; ++mt)
                af[mt] = __builtin_bit_cast(bf16x8,
                    *(const short8v*)(Ab + (wm * 64 + mt * 16 + c16) * 72 + ks + q * 8));
            #pragma unroll
            for (int nt = 0; nt < 2; ++nt)
                bfv[nt] = __builtin_bit_cast(bf16x8,
                    *(const short8v*)(Bb + (wn * 32 + nt * 16 + c16) * 72 + ks + q * 8));
            #pragma unroll
            for (int mt = 0; mt < 4; ++mt)
                #pragma unroll
                for (int nt = 0; nt < 2; ++nt)
                    acc[mt][nt] = __builtin_amdgcn_mfma_f32_16x16x32_bf16(
                        af[mt], bfv[nt], acc[mt][nt], 0, 0, 0);
        }
        if (kk + 1 < nsteps) __syncthreads();
    }
    // store (D frag: col = lane&15, row = (lane>>4)*4 + j)
    #pragma unroll
    for (int mt = 0; mt < 4; ++mt) {
        const int m = wm * 64 + mt * 16 + q * 4;
        #pragma unroll
        for (int nt = 0; nt < 2; ++nt) {
            const int n = n0 + wn * 32 + nt * 16 + c16;
            #pragma unroll
            for (int j = 0; j < 4; ++j)
                C[(size_t)(m + j) * ldc + n] = acc[mt][nt][j];
        }
    }
}

// GEMM1 (c@W1 -> P1 slabs) + GEMM3 (x@bdn -> P2 slabs), split-K 8, grid (16,8,2)
__global__ __launch_bounds__(256, 2) void gemm13_kernel(
    const unsigned short* __restrict__ cbf, const float* __restrict__ W1, float* __restrict__ P1,
    const unsigned short* __restrict__ xbf, const float* __restrict__ bdn, float* __restrict__ P2)
{
    const unsigned short* A = blockIdx.z ? xbf : cbf;
    const float* B = blockIdx.z ? bdn : W1;
    float* C = (blockIdx.z ? P2 : P1) + blockIdx.y * 131072;
    gemm_body<false>(A, B, C, 1024, 1024, 128, blockIdx.y * 128, blockIdx.x * 64);
}

// GEMM4: partials of y @ base_up^T, split-K 16, grid (16,16)
__global__ __launch_bounds__(256, 2) void gemm4_kernel(
    const unsigned short* __restrict__ ybf, const float* __restrict__ bup, float* __restrict__ P1)
{
    gemm_body<true>(ybf, bup, P1 + blockIdx.y * 131072, 1024, 1024, 64, blockIdx.y * 64, blockIdx.x * 64);
}

// ---------- hbf = bf16(gelu(sum P1 slabs + b1)), float4, 128 blocks ----------
__global__ __launch_bounds__(256) void hgen_kernel(
    const float* __restrict__ P, const float* __restrict__ bias, unsigned short* __restrict__ hbf)
{
    const int idx4 = blockIdx.x * 256 + threadIdx.x;   // float4 index over 131072 floats
    float4 s = ((const float4*)P)[idx4];
    #pragma unroll
    for (int p = 1; p < 8; ++p) {
        float4 v = ((const float4*)(P + p * 131072))[idx4];
        s.x += v.x; s.y += v.y; s.z += v.z; s.w += v.w;
    }
    float4 bb = ((const float4*)bias)[idx4 & 255];
    ushort4 o;
    o.x = f2bf(gelu_exact(s.x + bb.x));
    o.y = f2bf(gelu_exact(s.y + bb.y));
    o.z = f2bf(gelu_exact(s.z + bb.z));
    o.w = f2bf(gelu_exact(s.w + bb.w));
    ((ushort4*)hbf)[idx4] = o;
}

// ---------- GEMM2, A direct from L2 (no A LDS): wbf = bf16(hbf @ W2 + b2) ----------
__global__ __launch_bounds__(256, 2) void gemm2_kernel(
    const unsigned short* __restrict__ hbf, const float* __restrict__ W2,
    const float* __restrict__ b2, unsigned short* __restrict__ wbf)
{
    __shared__ __align__(16) unsigned short Bs[2][64 * 72];
    const int t = threadIdx.x;
    const int lane = t & 63, wid = t >> 6;
    const int wm = wid >> 1, wn = wid & 1;
    const int q = lane >> 4, c16 = lane & 15;
    const int n0 = blockIdx.x * 64;

    const int bnp = t & 31, bkc = t >> 5;
    const float* bptr = W2 + (size_t)(bkc * 8) * 32768 + n0 + bnp * 2;

    // A row pointers (global, L2-resident bf16)
    const unsigned short* arow[4];
    #pragma unroll
    for (int mt = 0; mt < 4; ++mt)
        arow[mt] = hbf + (wm * 64 + mt * 16 + c16) * 1024 + q * 8;

    float2 rb0, rb1, rb2, rb3, rb4, rb5, rb6, rb7;
    auto LOADB = [&](int kk) {
        const float* bp = bptr + (size_t)(kk << 6) * 32768;
        rb0 = *(const float2*)(bp);                       rb1 = *(const float2*)(bp + (size_t)32768);
        rb2 = *(const float2*)(bp + (size_t)2 * 32768);   rb3 = *(const float2*)(bp + (size_t)3 * 32768);
        rb4 = *(const float2*)(bp + (size_t)4 * 32768);   rb5 = *(const float2*)(bp + (size_t)5 * 32768);
        rb6 = *(const float2*)(bp + (size_t)6 * 32768);   rb7 = *(const float2*)(bp + (size_t)7 * 32768);
    };
    auto STOREB = [&](int buf) {
        short8v s0, s1;
        s0[0]=(short)f2bf(rb0.x); s1[0]=(short)f2bf(rb0.y);
        s0[1]=(short)f2bf(rb1.x); s1[1]=(short)f2bf(rb1.y);
        s0[2]=(short)f2bf(rb2.x); s1[2]=(short)f2bf(rb2.y);
        s0[3]=(short)f2bf(rb3.x); s1[3]=(short)f2bf(rb3.y);
        s0[4]=(short)f2bf(rb4.x); s1[4]=(short)f2bf(rb4.y);
        s0[5]=(short)f2bf(rb5.x); s1[5]=(short)f2bf(rb5.y);
        s0[6]=(short)f2bf(rb6.x); s1[6]=(short)f2bf(rb6.y);
        s0[7]=(short)f2bf(rb7.x); s1[7]=(short)f2bf(rb7.y);
        *(short8v*)(&Bs[buf][(bnp * 2 + 0) * 72 + bkc * 8]) = s0;
        *(short8v*)(&Bs[buf][(bnp * 2 + 1) * 72 + bkc * 8]) = s1;
    };

    f32x4 acc[4][2] = {};
    LOADB(0); STOREB(0); LOADB(1);
    __syncthreads();

    for (int kk = 0; kk < 16; ++kk) {
        if (kk + 1 < 16) STOREB((kk + 1) & 1);
        if (kk + 2 < 16) LOADB(kk + 2);
        const unsigned short* Bb = &Bs[kk & 1][0];
        #pragma unroll
        for (int ks = 0; ks < 64; ks += 32) {
            bf16x8 af[4], bfv[2];
            #pragma unroll
            for (int mt = 0; mt < 4; ++mt)
                af[mt] = __builtin_bit_cast(bf16x8,
                    *(const short8v*)(arow[mt] + kk * 64 + ks));
            #pragma unroll
            for (int nt = 0; nt < 2; ++nt)
                bfv[nt] = __builtin_bit_cast(bf16x8,
                    *(const short8v*)(Bb + (wn * 32 + nt * 16 + c16) * 72 + ks + q * 8));
            #pragma unroll
            for (int mt = 0; mt < 4; ++mt)
                #pragma unroll
                for (int nt = 0; nt < 2; ++nt)
                    acc[mt][nt] = __builtin_amdgcn_mfma_f32_16x16x32_bf16(
                        af[mt], bfv[nt], acc[mt][nt], 0, 0, 0);
        }
        if (kk + 1 < 16) __syncthreads();
    }
    #pragma unroll
    for (int mt = 0; mt < 4; ++mt) {
        const int m = wm * 64 + mt * 16 + q * 4;
        #pragma unroll
        for (int nt = 0; nt < 2; ++nt) {
            const int n = n0 + wn * 32 + nt * 16 + c16;
            const float bb = b2[n];
            #pragma unroll
            for (int j = 0; j < 4; ++j)
                wbf[(size_t)(m + j) * 32768 + n] = f2bf(acc[mt][nt][j] + bb);
        }
    }
}

// ---------- per-row fused epilogue: t2, y=gelu(.), ybf, t1, out_init ----------
__device__ __forceinline__ void block_reduce8(float a[8], float* out8, float (*scr)[8], int t) {
    #pragma unroll
    for (int r = 0; r < 8; ++r)
        #pragma unroll
        for (int off = 32; off; off >>= 1)
            a[r] += __shfl_xor(a[r], off);
    if ((t & 63) == 0) {
        #pragma unroll
        for (int r = 0; r < 8; ++r) scr[t >> 6][r] = a[r];
    }
    __syncthreads();
    if (t < 8) out8[t] = scr[0][t] + scr[1][t] + scr[2][t] + scr[3][t];
    __syncthreads();
}

__global__ __launch_bounds__(256) void e1big_kernel(
    const float* __restrict__ P2, const unsigned short* __restrict__ wbf,
    const float* __restrict__ x, unsigned short* __restrict__ ybf,
    float* __restrict__ out)
{
    __shared__ float scr[4][8];
    __shared__ float t2s[8], t1s[8];
    const int b = blockIdx.x, t = threadIdx.x;
    const unsigned short* wrow = wbf + (size_t)b * 32768;
    const float* xrow = x + b * 1024;

    // stage 1: t2[r] = sum_d la2[b,d,r] * x[b,d]   (la2 = chunk 2 @ +16384)
    float a[8] = {0,0,0,0,0,0,0,0};
    #pragma unroll
    for (int i = 0; i < 4; ++i) {
        int d = t + i * 256;
        float xv = xrow[d];
        short8v wv = *(const short8v*)(wrow + 16384 + d * 8);
        #pragma unroll
        for (int r = 0; r < 8; ++r) a[r] += xv * bf2f((unsigned short)wv[r]);
    }
    block_reduce8(a, t2s, scr, t);
    float t2v[8];
    #pragma unroll
    for (int r = 0; r < 8; ++r) t2v[r] = t2s[r];

    // stage 2: y = gelu(sum P2 slabs + lb2 @ t2); accumulate t1 = sum_l lb1[l,:]*y[l]
    float a1[8] = {0,0,0,0,0,0,0,0};
    #pragma unroll
    for (int i = 0; i < 4; ++i) {
        int l = t + i * 256;
        float s = 0.0f;
        #pragma unroll
        for (int p = 0; p < 8; ++p) s += P2[p * 131072 + b * 1024 + l];
        short8v w2v = *(const short8v*)(wrow + 24576 + l * 8);
        #pragma unroll
        for (int r = 0; r < 8; ++r) s += bf2f((unsigned short)w2v[r]) * t2v[r];
        float y = gelu_exact(s);
        ybf[b * 1024 + l] = f2bf(y);
        short8v w1v = *(const short8v*)(wrow + 8192 + l * 8);
        #pragma unroll
        for (int r = 0; r < 8; ++r) a1[r] += y * bf2f((unsigned short)w1v[r]);
    }
    block_reduce8(a1, t1s, scr, t);
    float t1v[8];
    #pragma unroll
    for (int r = 0; r < 8; ++r) t1v[r] = t1s[r];

    // stage 3: out_init = x + la1 @ t1   (la1 = chunk 0)
    #pragma unroll
    for (int i = 0; i < 4; ++i) {
        int k = t + i * 256;
        short8v w0v = *(const short8v*)(wrow + k * 8);
        float s = xrow[k];
        #pragma unroll
        for (int r = 0; r < 8; ++r) s += bf2f((unsigned short)w0v[r]) * t1v[r];
        out[b * 1024 + k] = s;
    }
}

// ---------- out += sum GEMM4 partials (16 slabs), float4, 128 blocks ----------
__global__ __launch_bounds__(256) void e2f_kernel(
    const float* __restrict__ P1, float* __restrict__ out)
{
    const int idx4 = blockIdx.x * 256 + threadIdx.x;
    float4 o = ((float4*)out)[idx4];
    #pragma unroll
    for (int p = 0; p < 16; ++p) {
        float4 v = ((const float4*)(P1 + p * 131072))[idx4];
        o.x += v.x; o.y += v.y; o.z += v.z; o.w += v.w;
    }
    ((float4*)out)[idx4] = o;
}

extern "C" void kernel_launch(void* const* d_in, const int* in_sizes, int n_in,
                              void* d_out, int out_size, void* d_ws, size_t ws_size,
                              hipStream_t stream) {
    (void)in_sizes; (void)n_in; (void)out_size; (void)ws_size;
    const float* x        = (const float*)d_in[0];
    const float* ada      = (const float*)d_in[1];
    const float* bup      = (const float*)d_in[2];
    const float* bdn      = (const float*)d_in[3];
    const float* ln_g     = (const float*)d_in[4];
    const float* ln_b     = (const float*)d_in[5];
    const float* W1       = (const float*)d_in[6];
    const float* b1       = (const float*)d_in[7];
    const float* W2       = (const float*)d_in[8];
    const float* b2       = (const float*)d_in[9];

    char* ws = (char*)d_ws;
    unsigned short* wbf = (unsigned short*)(ws + 0);         // 8 MiB
    float* P1           = (float*)(ws + 8388608);            // 8 MiB (16 slabs; gemm1 uses 8)
    float* P2           = (float*)(ws + 16777216);           // 4 MiB (8 slabs)
    unsigned short* cbf = (unsigned short*)(ws + 20971520);  // 256 KiB each
    unsigned short* xbf = (unsigned short*)(ws + 21233664);
    unsigned short* hbf = (unsigned short*)(ws + 21495808);
    unsigned short* ybf = (unsigned short*)(ws + 21757952);

    // 1. LN + bf16 casts
    ln_cast_kernel<<<128, 256, 0, stream>>>(ada, ln_g, ln_b, x, cbf, xbf);
    // 2. GEMM1 (c@W1 -> P1) + GEMM3 (x@bdn -> P2), split-K 8, one launch
    gemm13_kernel<<<dim3(16, 8, 2), 256, 0, stream>>>(cbf, W1, P1, xbf, bdn, P2);
    // 3. hbf = bf16(gelu(sum P1 + b1))
    hgen_kernel<<<128, 256, 0, stream>>>(P1, b1, hbf);
    // 4. GEMM2 (A direct from L2): wbf = bf16(hbf @ W2 + b2)
    gemm2_kernel<<<512, 256, 0, stream>>>(hbf, W2, b2, wbf);
    // 5. fused row epilogue: t2, y, ybf, t1, out = x + la1@t1
    e1big_kernel<<<128, 256, 0, stream>>>(P2, wbf, x, ybf, (float*)d_out);
    // 6. GEMM4: partials of y @ bup^T -> P1 (split-K 16)
    gemm4_kernel<<<dim3(16, 16), 256, 0, stream>>>(ybf, bup, P1);
    // 7. out += sum partials
    e2f_kernel<<<128, 256, 0, stream>>>(P1, (float*)d_out);
}